// Round 13
// baseline (188.731 us; speedup 1.0000x reference)
//
#include <hip/hip_runtime.h>

typedef __bf16 bf16;
typedef __bf16 bf16x4 __attribute__((ext_vector_type(4)));
typedef __bf16 bf16x8 __attribute__((ext_vector_type(8)));
typedef float f32x4 __attribute__((ext_vector_type(4)));

#define NHEADS 16
#define HDIM 64
#define SEQ 2048
#define BATCH 4
#define DMODEL 1024
#define NTOK (BATCH * SEQ)
#define KVBLK 64
// softmax constants: p = exp(s/8 - 20) = exp2( (q*QS)·k + C0 )
#define QSCALE 0.18033688f            /* 0.125 * log2(e) */
#define C0EXP  -28.853901f            /* -20 * log2(e)   */

typedef void gvoid __attribute__((address_space(1)));
typedef void lvoid __attribute__((address_space(3)));

__device__ __forceinline__ f32x4 mfma16(bf16x8 a, bf16x8 b, f32x4 c) {
  return __builtin_amdgcn_mfma_f32_16x16x32_bf16(a, b, c, 0, 0, 0);
}

__device__ __forceinline__ void gload16(const bf16* g, bf16* l) {
  __builtin_amdgcn_global_load_lds((gvoid*)g, (lvoid*)l, 16, 0, 0);
}

// ---------------- f32 -> bf16 bulk convert (8 elems/thread) ----------------
__global__ __launch_bounds__(256) void cvt_f32_bf16(
    const float* __restrict__ in, bf16* __restrict__ out, long n) {
  const long i = ((long)blockIdx.x * 256 + threadIdx.x) * 8;
  if (i >= n) return;
  const float4 a = *(const float4*)(in + i);
  const float4 b = *(const float4*)(in + i + 4);
  bf16x8 o;
  o[0] = (bf16)a.x; o[1] = (bf16)a.y; o[2] = (bf16)a.z; o[3] = (bf16)a.w;
  o[4] = (bf16)b.x; o[5] = (bf16)b.y; o[6] = (bf16)b.z; o[7] = (bf16)b.w;
  *(bf16x8*)(out + i) = o;
}

// -------- weight transpose + convert: in f32[K,N] -> out bf16[N,K] --------
__global__ __launch_bounds__(256) void transpose_cvt(
    const float* __restrict__ in, bf16* __restrict__ out, int K, int N) {
  __shared__ float t[32][33];
  const int n0 = blockIdx.x * 32, k0 = blockIdx.y * 32;
  for (int i = threadIdx.y; i < 32; i += 8)
    t[i][threadIdx.x] = in[(long)(k0 + i) * N + n0 + threadIdx.x];
  __syncthreads();
  for (int i = threadIdx.y; i < 32; i += 8)
    out[(long)(n0 + i) * K + k0 + threadIdx.x] = (bf16)t[threadIdx.x][i];
}

// ---------------- GEMM: D = A[M,K] * Bt[N,K]^T + bias ----------------
// 3-buffer LDS pipeline, counted vmcnt(4), one raw s_barrier per K-step.
// LDS fragment reads XOR-swizzled; inverse swizzle pre-applied to the
// global source column; linear gload_lds dest.
// Epilogue (MODE 3/4): acc tile staged through LDS [128][136], then 8x
// coalesced b128 global stores per thread. V-blocks write LDS transposed.
// MODE 0: plain row-major [M,N] f32 output, scatter epilogue.
// MODE 3: fused Q|C. col<1024: Q -> [B,H,S,64] scaled by QSCALE; else C.
// MODE 4: fused K|V. col<1024: K -> [B,H,S,64]; else V -> [B,H,64,S].
template <int MODE, typename OutT>
__global__ __launch_bounds__(256) void gemm_bt(
    const bf16* __restrict__ A, const bf16* __restrict__ Bt,
    const float* __restrict__ bias, const float* __restrict__ bias2,
    OutT* __restrict__ D, bf16* __restrict__ D2, int N, int K) {
  __shared__ bf16 smem[3 * 4096 * 2];   // 48KB: As[3][4096] | Bs[3][4096]
  bf16* const AsB = smem;
  bf16* const BsB = smem + 3 * 4096;
  const int tid = threadIdx.x;
  const int lane = tid & 63;
  const int wave = tid >> 6;
  const int wr = (wave >> 1) * 64;
  const int wc = (wave & 1) * 64;
  const int r16 = lane & 15;
  const int kg = lane >> 4;
  const long rowBase = (long)blockIdx.x * 128;
  const long colBase = (long)blockIdx.y * 128;

  const int o0 = tid * 16;          // byte offset into the 8KB tile
  const int o1 = o0 + 4096;
  const int ra0 = o0 >> 6, ra1 = o1 >> 6;
  const int ca0 = ((o0 & 63) ^ (((ra0 >> 1) & 3) << 4)) >> 1;
  const int ca1 = ((o1 & 63) ^ (((ra1 >> 1) & 3) << 4)) >> 1;
  const bf16* pA0 = A + (rowBase + ra0) * K + ca0;
  const bf16* pA1 = A + (rowBase + ra1) * K + ca1;
  const bf16* pB0 = Bt + (colBase + ra0) * K + ca0;
  const bf16* pB1 = Bt + (colBase + ra1) * K + ca1;
  const int e0 = o0 >> 1, e1 = o1 >> 1;

  auto gaddr = [](const bf16* base, int row, int bytecol) -> const bf16* {
    return base + row * 32 + ((bytecol ^ (((row >> 1) & 3) << 4)) >> 1);
  };

  f32x4 acc[4][4] = {};
  const int nk = K >> 5;

#define GSTAGE(kt_)                                        \
  {                                                        \
    const int b_ = (kt_) % 3;                              \
    const int o_ = (kt_) * 32;                             \
    gload16(pA0 + o_, AsB + b_ * 4096 + e0);               \
    gload16(pA1 + o_, AsB + b_ * 4096 + e1);               \
    gload16(pB0 + o_, BsB + b_ * 4096 + e0);               \
    gload16(pB1 + o_, BsB + b_ * 4096 + e1);               \
  }

  GSTAGE(0);
  GSTAGE(1);
  asm volatile("s_waitcnt vmcnt(4)" ::: "memory");  // tile 0 landed (self)
  asm volatile("s_barrier" ::: "memory");           // -> landed for all

  for (int kt = 0; kt < nk; ++kt) {
    if (kt + 2 < nk) {
      GSTAGE(kt + 2);
      asm volatile("s_waitcnt vmcnt(4)" ::: "memory");  // tile kt+1 landed
    } else {
      asm volatile("s_waitcnt vmcnt(0)" ::: "memory");
    }
    const bf16* as = AsB + (kt % 3) * 4096;
    const bf16* bs = BsB + (kt % 3) * 4096;
    bf16x8 af[4], bfr[4];
#pragma unroll
    for (int m = 0; m < 4; ++m)
      af[m] = *(const bf16x8*)gaddr(as, wr + m * 16 + r16, kg * 16);
#pragma unroll
    for (int n = 0; n < 4; ++n)
      bfr[n] = *(const bf16x8*)gaddr(bs, wc + n * 16 + r16, kg * 16);
    __builtin_amdgcn_s_setprio(1);
#pragma unroll
    for (int m = 0; m < 4; ++m)
#pragma unroll
      for (int n = 0; n < 4; ++n)
        acc[m][n] = mfma16(af[m], bfr[n], acc[m][n]);
    __builtin_amdgcn_s_setprio(0);
    asm volatile("s_barrier" ::: "memory");
  }
#undef GSTAGE

  if (MODE == 0) {
#pragma unroll
    for (int n = 0; n < 4; ++n) {
      const long col = colBase + wc + n * 16 + r16;
      const float bvv = bias[col];
#pragma unroll
      for (int m = 0; m < 4; ++m) {
        const long row0 = rowBase + wr + m * 16 + kg * 4;
#pragma unroll
        for (int r = 0; r < 4; ++r)
          D[(row0 + r) * N + col] = (OutT)(acc[m][n][r] + bvv);
      }
    }
  } else {
    // ---- LDS-staged coalesced epilogue ----
    const bool tr = (MODE == 4) && (colBase >= 1024);  // V^T blocks
    bf16* E = smem;  // [128][136] bf16 (staging LDS is dead)
#pragma unroll
    for (int n = 0; n < 4; ++n) {
      const int cl = wc + n * 16 + r16;
      const long col = colBase + cl;
      const bool primary = col < 1024;
      const float bvv = primary ? bias[col] : bias2[col - 1024];
#pragma unroll
      for (int m = 0; m < 4; ++m) {
#pragma unroll
        for (int r = 0; r < 4; ++r) {
          const int rl = wr + m * 16 + kg * 4 + r;
          float v = acc[m][n][r] + bvv;
          if (MODE == 3 && primary) v *= QSCALE;
          if (tr) E[cl * 136 + rl] = (bf16)v;
          else    E[rl * 136 + cl] = (bf16)v;
        }
      }
    }
    __syncthreads();
    const int er = tid >> 1;          // 0..127 logical row of stored layout
    const int c0 = (tid & 1) * 64;    // 64-elem chunk
    const long brow = rowBase >> 11;  // batch index (tile never straddles)
    const int srow = (int)(rowBase & 2047);
    bf16* dp;
    if (!tr) {
      if (colBase < 1024) {  // Q or K head-split: contiguous along d
        const long col = colBase + c0;
        dp = (bf16*)(void*)D +
             (((brow * NHEADS + (col >> 6)) * SEQ) + srow + er) * HDIM;
      } else {               // C row-major [8192,256]
        dp = D2 + (long)(rowBase + er) * 256 + (colBase - 1024) + c0;
      }
    } else {                 // V^T: contiguous along s
      const long c2 = colBase - 1024 + er;
      dp = D2 + ((brow * NHEADS + (c2 >> 6)) * HDIM + (c2 & 63)) * SEQ +
           srow + c0;
    }
    const bf16* Er = E + er * 136 + c0;
#pragma unroll
    for (int j = 0; j < 8; ++j)
      *(bf16x8*)(dp + j * 8) = *(const bf16x8*)(Er + j * 8);
  }
}

// ---------------- fused non-causal flash attention ----------------
// 512 blocks; XCD-bijective swizzle (8 q-blocks of one head -> 1 XCD).
// 256 threads = 4 waves, each wave owns 64 q-rows (qm=4): K/V fragment
// reads amortize over 2x more MFMA -> block LDS traffic/tile 208->144KB.
// K/V staged into 3-buffer LDS (counted vmcnt(4), one s_barrier/tile);
// K/V reads XOR-swizzled. SWAPPED QK^T (sc = mfma(K,Q) -> D[k][q]):
// one ds_write_b64 per (qm,kt). Row-sum: f32x4 psumv (4-deep chains),
// end-only shfl reduce. Fixed-max softmax: Q pre-scaled, acc starts at
// C0EXP, p = v_exp2(sc). LDS = 48K KV + 32K P = 80KB -> 2 blocks/CU.
__global__ __launch_bounds__(256, 2) void mla_attn(
    const bf16* __restrict__ Q, const bf16* __restrict__ Kg,
    const bf16* __restrict__ Vt, bf16* __restrict__ Out) {
  __shared__ bf16 Kl[3][KVBLK * HDIM];   // 8KB per buf
  __shared__ bf16 Vl[3][HDIM * KVBLK];   // 8KB per buf
  __shared__ bf16 Pl[4][64][64];         // per-wave P tile, swizzled
  const int tid = threadIdx.x;
  const int lane = tid & 63;
  const int w = tid >> 6;
  const int r16 = lane & 15;
  const int kg = lane >> 4;
  // XCD swizzle: physical bid -> logical lb; 8 blocks of a head -> 1 XCD
  const int bid = (int)blockIdx.x;
  const int lb = (bid & 7) * 64 + (bid >> 3);
  const int qb = lb & 7;            // S/256 = 8
  const int bh = lb >> 3;           // b*16 + h
  const bf16* Qp = Q + (long)bh * SEQ * HDIM;
  const bf16* Kp = Kg + (long)bh * SEQ * HDIM;
  const bf16* Vp = Vt + (long)bh * HDIM * SEQ;
  const int q0 = qb * 256 + w * 64;

  // staging: thread stages 2x16B of K and 2x16B of V per tile.
  const int so0 = tid * 16;                                   // 0..4095
  const int so1 = so0 + 4096;                                 // 4096..8191
  const int sr0 = so0 >> 7, sr1 = so1 >> 7;
  const int sc0 = ((so0 & 127) ^ ((sr0 & 7) << 4)) >> 1;
  const int sc1 = ((so1 & 127) ^ ((sr1 & 7) << 4)) >> 1;
  const bf16* KgS0 = Kp + (long)sr0 * HDIM + sc0;             // + kv*HDIM
  const bf16* KgS1 = Kp + (long)sr1 * HDIM + sc1;
  const bf16* VgS0 = Vp + (long)sr0 * SEQ + sc0;              // + kv
  const bf16* VgS1 = Vp + (long)sr1 * SEQ + sc1;
  const int se0 = so0 >> 1, se1 = so1 >> 1;

  // Q fragments [qm][kslice] (already scaled by QSCALE)
  bf16x8 aq[4][2];
#pragma unroll
  for (int qm = 0; qm < 4; ++qm) {
    const bf16* qp = Qp + (long)(q0 + qm * 16 + r16) * HDIM + kg * 8;
    aq[qm][0] = *(const bf16x8*)qp;
    aq[qm][1] = *(const bf16x8*)(qp + 32);
  }

  f32x4 accO[4][4];
  f32x4 psumv[4];
#pragma unroll
  for (int qm = 0; qm < 4; ++qm) {
    psumv[qm] = (f32x4){0.f, 0.f, 0.f, 0.f};
#pragma unroll
    for (int dt = 0; dt < 4; ++dt) accO[qm][dt] = (f32x4){0.f, 0.f, 0.f, 0.f};
  }
  const f32x4 c0v = {C0EXP, C0EXP, C0EXP, C0EXP};

  // swizzled K/V LDS read address (elements)
  auto kaddr = [](const bf16* base, int row, int bytecol) -> const bf16* {
    return base + row * 64 + ((bytecol ^ ((row & 7) << 4)) >> 1);
  };

#define ASTAGE(t_)                                                   \
  {                                                                  \
    const int b_ = (t_) % 3;                                         \
    const long off_ = (long)(t_) * KVBLK;                            \
    gload16(KgS0 + off_ * HDIM, (bf16*)Kl[b_] + se0);                \
    gload16(KgS1 + off_ * HDIM, (bf16*)Kl[b_] + se1);                \
    gload16(VgS0 + off_, (bf16*)Vl[b_] + se0);                       \
    gload16(VgS1 + off_, (bf16*)Vl[b_] + se1);                       \
  }

  ASTAGE(0);
  ASTAGE(1);
  asm volatile("s_waitcnt vmcnt(4)" ::: "memory");  // tile 0 landed (self)
  asm volatile("s_barrier" ::: "memory");           // -> landed for all

  const int NT = SEQ / KVBLK;
  for (int t = 0; t < NT; ++t) {
    if (t + 2 < NT) {
      ASTAGE(t + 2);
      asm volatile("s_waitcnt vmcnt(4)" ::: "memory");  // tile t+1 landed
    } else {
      asm volatile("s_waitcnt vmcnt(0)" ::: "memory");
    }
    const bf16* kl = Kl[t % 3];
    const bf16* vl = Vl[t % 3];
    // ---- hoist K fragments once (shared by all 4 qm) ----
    bf16x8 kf[4][2];
#pragma unroll
    for (int kt = 0; kt < 4; ++kt) {
      const int row = kt * 16 + r16;
      kf[kt][0] = *(const bf16x8*)kaddr(kl, row, kg * 16);
      kf[kt][1] = *(const bf16x8*)kaddr(kl, row, 64 + kg * 16);
    }
    // ---- per-qm: QK^T swapped + softmax + packed P store ----
#pragma unroll
    for (int qm = 0; qm < 4; ++qm) {
      f32x4 sc[4];
      __builtin_amdgcn_s_setprio(1);
#pragma unroll
      for (int kt = 0; kt < 4; ++kt) {
        f32x4 tv = mfma16(kf[kt][0], aq[qm][0], c0v);
        tv = mfma16(kf[kt][1], aq[qm][1], tv);
        sc[kt] = tv;  // k = kt*16+kg*4+r, q = qm*16+r16
      }
      __builtin_amdgcn_s_setprio(0);
      bf16* prow = &Pl[w][qm * 16 + r16][0];
      const int sw = (r16 & 7) << 4;   // byte swizzle
#pragma unroll
      for (int kt = 0; kt < 4; ++kt) {
        bf16x4 pk;
        f32x4 pv;
#pragma unroll
        for (int r = 0; r < 4; ++r) {
          pv[r] = __builtin_amdgcn_exp2f(sc[kt][r]);
          pk[r] = (bf16)pv[r];
        }
        psumv[qm] += pv;
        *(bf16x4*)((char*)prow + ((kt * 32 + kg * 8) ^ sw)) = pk;
      }
    }
    // ---- PV ----
    __builtin_amdgcn_s_setprio(1);
#pragma unroll
    for (int kc = 0; kc < 2; ++kc) {
      bf16x8 ap[4];
#pragma unroll
      for (int qm = 0; qm < 4; ++qm) {
        const bf16* prow = &Pl[w][qm * 16 + r16][0];
        const int sw = (r16 & 7) << 4;
        ap[qm] = *(const bf16x8*)((const char*)prow + ((kc * 64 + kg * 16) ^ sw));
      }
#pragma unroll
      for (int dt = 0; dt < 4; ++dt) {
        const int vrow = dt * 16 + r16;
        const bf16x8 vf = *(const bf16x8*)kaddr(vl, vrow, kc * 64 + kg * 16);
#pragma unroll
        for (int qm = 0; qm < 4; ++qm)
          accO[qm][dt] = mfma16(ap[qm], vf, accO[qm][dt]);
      }
    }
    __builtin_amdgcn_s_setprio(0);
    asm volatile("s_barrier" ::: "memory");
  }
#undef ASTAGE

  // finish row-sums: component-sum, then combine across kg groups.
  float ps[4];
#pragma unroll
  for (int qm = 0; qm < 4; ++qm) {
    ps[qm] = psumv[qm][0] + psumv[qm][1] + psumv[qm][2] + psumv[qm][3];
    ps[qm] += __shfl_xor(ps[qm], 16);
    ps[qm] += __shfl_xor(ps[qm], 32);   // now rowsum(q=r16) on all lanes
  }
  const int b = bh >> 4, h = bh & 15;
#pragma unroll
  for (int qm = 0; qm < 4; ++qm)
#pragma unroll
    for (int r = 0; r < 4; ++r) {
      // rowsum for q = qm*16 + kg*4 + r lives at lane (kg*4 + r)
      const float inv = 1.f / __shfl(ps[qm], kg * 4 + r);
      const long qrow = q0 + qm * 16 + kg * 4 + r;
      bf16* op = Out + ((long)b * SEQ + qrow) * DMODEL + h * HDIM;
#pragma unroll
      for (int dt = 0; dt < 4; ++dt)
        op[dt * 16 + r16] = (bf16)(accO[qm][dt][r] * inv);
    }
}

// ---------------- launcher ----------------
extern "C" void kernel_launch(void* const* d_in, const int* in_sizes, int n_in,
                              void* d_out, int out_size, void* d_ws, size_t ws_size,
                              hipStream_t stream) {
  const float* x  = (const float*)d_in[0];
  const float* Wc = (const float*)d_in[1];
  const float* bc = (const float*)d_in[2];
  const float* Wk = (const float*)d_in[3];
  const float* bk = (const float*)d_in[4];
  const float* Wv = (const float*)d_in[5];
  const float* bv = (const float*)d_in[6];
  const float* Wq = (const float*)d_in[7];
  const float* bq = (const float*)d_in[8];
  const float* Wo = (const float*)d_in[9];
  const float* bo = (const float*)d_in[10];
  float* out = (float*)d_out;

  bf16* p = (bf16*)d_ws;
  bf16* xb   = p; p += (long)NTOK * 1024;   // also reused as AO
  bf16* WqcT = p; p += 1280 * 1024;         // Wq^T rows 0..1023, Wc^T rows 1024..1279
  bf16* WkvT = p; p += 2048 * 256;          // Wk^T rows 0..1023, Wv^T rows 1024..2047
  bf16* WoT  = p; p += 1024 * 1024;
  bf16* Qb   = p; p += (long)NTOK * 1024;
  bf16* Kb   = p; p += (long)NTOK * 1024;
  bf16* Vtb  = p; p += (long)NTOK * 1024;
  bf16* Cb   = p; p += (long)NTOK * 256;
  bf16* AO   = xb;  // alias: x is dead after the QC GEMM

  cvt_f32_bf16<<<(long)NTOK * 1024 / (256 * 8), 256, 0, stream>>>(x, xb, (long)NTOK * 1024);

  dim3 tt(32, 8);
  transpose_cvt<<<dim3(32, 32), tt, 0, stream>>>(Wq, WqcT, 1024, 1024);
  transpose_cvt<<<dim3(8, 32),  tt, 0, stream>>>(Wc, WqcT + 1024 * 1024, 1024, 256);
  transpose_cvt<<<dim3(32, 8),  tt, 0, stream>>>(Wk, WkvT, 256, 1024);
  transpose_cvt<<<dim3(32, 8),  tt, 0, stream>>>(Wv, WkvT + 1024 * 256, 256, 1024);
  transpose_cvt<<<dim3(32, 32), tt, 0, stream>>>(Wo, WoT, 1024, 1024);

  // fused Q|C: Q -> [B,H,S,64] (scaled), C -> [8192,256]
  gemm_bt<3, bf16><<<dim3(64, 10), 256, 0, stream>>>(xb, WqcT, bq, bc, Qb, Cb, 1280, 1024);
  // fused K|V: K -> [B,H,S,64], V -> [B,H,64,S]
  gemm_bt<4, bf16><<<dim3(64, 16), 256, 0, stream>>>(Cb, WkvT, bk, bv, Kb, Vtb, 2048, 256);

  mla_attn<<<(SEQ / 256) * BATCH * NHEADS, 256, 0, stream>>>(Qb, Kb, Vtb, AO);

  // out = AO*Wo+bo -> f32 [8192,1024]
  gemm_bt<0, float><<<dim3(64, 8), 256, 0, stream>>>(AO, WoT, bo, bo, out, (bf16*)nullptr, 1024, 1024);
}

// Round 14
// 171.320 us; speedup vs baseline: 1.1016x; 1.1016x over previous
//
#include <hip/hip_runtime.h>

typedef __bf16 bf16;
typedef __bf16 bf16x4 __attribute__((ext_vector_type(4)));
typedef __bf16 bf16x8 __attribute__((ext_vector_type(8)));
typedef float f32x4 __attribute__((ext_vector_type(4)));

#define NHEADS 16
#define HDIM 64
#define SEQ 2048
#define BATCH 4
#define DMODEL 1024
#define NTOK (BATCH * SEQ)
#define KVBLK 64
// softmax constants: p = exp(s/8 - 20) = exp2( (q*QS)·k + C0 )
#define QSCALE 0.18033688f            /* 0.125 * log2(e) */
#define C0EXP  -28.853901f            /* -20 * log2(e)   */

typedef void gvoid __attribute__((address_space(1)));
typedef void lvoid __attribute__((address_space(3)));

__device__ __forceinline__ f32x4 mfma16(bf16x8 a, bf16x8 b, f32x4 c) {
  return __builtin_amdgcn_mfma_f32_16x16x32_bf16(a, b, c, 0, 0, 0);
}

__device__ __forceinline__ void gload16(const bf16* g, bf16* l) {
  __builtin_amdgcn_global_load_lds((gvoid*)g, (lvoid*)l, 16, 0, 0);
}

// ---------------- fused prep: x cvt + all 5 weight transposes ----------------
// one launch, 6912 blocks x 256 threads:
//   [0,1024)    Wq  1024x1024 -> WqcT
//   [1024,1280) Wc  1024x256  -> WqcT + 1024*1024
//   [1280,1536) Wk  256x1024  -> WkvT
//   [1536,1792) Wv  256x1024  -> WkvT + 1024*256
//   [1792,2816) Wo  1024x1024 -> WoT
//   [2816,6912) cvt x (f32 -> bf16), 2048 elems/block
__device__ __forceinline__ void tr32(const float* in, bf16* out, int K, int N,
                                     int bx, int by, int tid) {
  __shared__ float t[32][33];
  const int x = tid & 31, y = tid >> 5;
  const int n0 = bx * 32, k0 = by * 32;
  for (int i = y; i < 32; i += 8)
    t[i][x] = in[(long)(k0 + i) * N + n0 + x];
  __syncthreads();
  for (int i = y; i < 32; i += 8)
    out[(long)(n0 + i) * K + k0 + x] = (bf16)t[x][i];
}

__global__ __launch_bounds__(256) void prep_all(
    const float* __restrict__ x,  const float* __restrict__ Wc,
    const float* __restrict__ Wk, const float* __restrict__ Wv,
    const float* __restrict__ Wq, const float* __restrict__ Wo,
    bf16* __restrict__ xb, bf16* __restrict__ WqcT,
    bf16* __restrict__ WkvT, bf16* __restrict__ WoT) {
  const int b = blockIdx.x;
  const int tid = threadIdx.x;
  if (b < 1024) {
    tr32(Wq, WqcT, 1024, 1024, b & 31, b >> 5, tid);
  } else if (b < 1280) {
    const int bb = b - 1024;
    tr32(Wc, WqcT + 1024 * 1024, 1024, 256, bb & 7, bb >> 3, tid);
  } else if (b < 1536) {
    const int bb = b - 1280;
    tr32(Wk, WkvT, 256, 1024, bb & 31, bb >> 5, tid);
  } else if (b < 1792) {
    const int bb = b - 1536;
    tr32(Wv, WkvT + 1024 * 256, 256, 1024, bb & 31, bb >> 5, tid);
  } else if (b < 2816) {
    const int bb = b - 1792;
    tr32(Wo, WoT, 1024, 1024, bb & 31, bb >> 5, tid);
  } else {
    const long i = ((long)(b - 2816) * 256 + tid) * 8;
    const float4 a = *(const float4*)(x + i);
    const float4 c = *(const float4*)(x + i + 4);
    bf16x8 o;
    o[0] = (bf16)a.x; o[1] = (bf16)a.y; o[2] = (bf16)a.z; o[3] = (bf16)a.w;
    o[4] = (bf16)c.x; o[5] = (bf16)c.y; o[6] = (bf16)c.z; o[7] = (bf16)c.w;
    *(bf16x8*)(xb + i) = o;
  }
}

// ---------------- GEMM: D = A[M,K] * Bt[N,K]^T + bias ----------------
// 3-buffer LDS pipeline, counted vmcnt(4), one raw s_barrier per K-step.
// LDS fragment reads XOR-swizzled; inverse swizzle pre-applied to the
// global source column; linear gload_lds dest.
// Epilogue (MODE 3/4): acc tile staged through LDS [128][136], then 8x
// coalesced b128 global stores per thread. V-blocks write LDS transposed.
// MODE 0: plain row-major [M,N] f32 output, scatter epilogue.
// MODE 3: fused Q|C. col<1024: Q -> [B,H,S,64] scaled by QSCALE; else C.
// MODE 4: fused K|V. col<1024: K -> [B,H,S,64]; else V -> [B,H,64,S].
template <int MODE, typename OutT>
__global__ __launch_bounds__(256) void gemm_bt(
    const bf16* __restrict__ A, const bf16* __restrict__ Bt,
    const float* __restrict__ bias, const float* __restrict__ bias2,
    OutT* __restrict__ D, bf16* __restrict__ D2, int N, int K) {
  __shared__ bf16 smem[3 * 4096 * 2];   // 48KB: As[3][4096] | Bs[3][4096]
  bf16* const AsB = smem;
  bf16* const BsB = smem + 3 * 4096;
  const int tid = threadIdx.x;
  const int lane = tid & 63;
  const int wave = tid >> 6;
  const int wr = (wave >> 1) * 64;
  const int wc = (wave & 1) * 64;
  const int r16 = lane & 15;
  const int kg = lane >> 4;
  const long rowBase = (long)blockIdx.x * 128;
  const long colBase = (long)blockIdx.y * 128;

  const int o0 = tid * 16;          // byte offset into the 8KB tile
  const int o1 = o0 + 4096;
  const int ra0 = o0 >> 6, ra1 = o1 >> 6;
  const int ca0 = ((o0 & 63) ^ (((ra0 >> 1) & 3) << 4)) >> 1;
  const int ca1 = ((o1 & 63) ^ (((ra1 >> 1) & 3) << 4)) >> 1;
  const bf16* pA0 = A + (rowBase + ra0) * K + ca0;
  const bf16* pA1 = A + (rowBase + ra1) * K + ca1;
  const bf16* pB0 = Bt + (colBase + ra0) * K + ca0;
  const bf16* pB1 = Bt + (colBase + ra1) * K + ca1;
  const int e0 = o0 >> 1, e1 = o1 >> 1;

  auto gaddr = [](const bf16* base, int row, int bytecol) -> const bf16* {
    return base + row * 32 + ((bytecol ^ (((row >> 1) & 3) << 4)) >> 1);
  };

  f32x4 acc[4][4] = {};
  const int nk = K >> 5;

#define GSTAGE(kt_)                                        \
  {                                                        \
    const int b_ = (kt_) % 3;                              \
    const int o_ = (kt_) * 32;                             \
    gload16(pA0 + o_, AsB + b_ * 4096 + e0);               \
    gload16(pA1 + o_, AsB + b_ * 4096 + e1);               \
    gload16(pB0 + o_, BsB + b_ * 4096 + e0);               \
    gload16(pB1 + o_, BsB + b_ * 4096 + e1);               \
  }

  GSTAGE(0);
  GSTAGE(1);
  asm volatile("s_waitcnt vmcnt(4)" ::: "memory");  // tile 0 landed (self)
  asm volatile("s_barrier" ::: "memory");           // -> landed for all

  for (int kt = 0; kt < nk; ++kt) {
    if (kt + 2 < nk) {
      GSTAGE(kt + 2);
      asm volatile("s_waitcnt vmcnt(4)" ::: "memory");  // tile kt+1 landed
    } else {
      asm volatile("s_waitcnt vmcnt(0)" ::: "memory");
    }
    const bf16* as = AsB + (kt % 3) * 4096;
    const bf16* bs = BsB + (kt % 3) * 4096;
    bf16x8 af[4], bfr[4];
#pragma unroll
    for (int m = 0; m < 4; ++m)
      af[m] = *(const bf16x8*)gaddr(as, wr + m * 16 + r16, kg * 16);
#pragma unroll
    for (int n = 0; n < 4; ++n)
      bfr[n] = *(const bf16x8*)gaddr(bs, wc + n * 16 + r16, kg * 16);
    __builtin_amdgcn_s_setprio(1);
#pragma unroll
    for (int m = 0; m < 4; ++m)
#pragma unroll
      for (int n = 0; n < 4; ++n)
        acc[m][n] = mfma16(af[m], bfr[n], acc[m][n]);
    __builtin_amdgcn_s_setprio(0);
    asm volatile("s_barrier" ::: "memory");
  }
#undef GSTAGE

  if (MODE == 0) {
#pragma unroll
    for (int n = 0; n < 4; ++n) {
      const long col = colBase + wc + n * 16 + r16;
      const float bvv = bias[col];
#pragma unroll
      for (int m = 0; m < 4; ++m) {
        const long row0 = rowBase + wr + m * 16 + kg * 4;
#pragma unroll
        for (int r = 0; r < 4; ++r)
          D[(row0 + r) * N + col] = (OutT)(acc[m][n][r] + bvv);
      }
    }
  } else {
    // ---- LDS-staged coalesced epilogue ----
    const bool tr = (MODE == 4) && (colBase >= 1024);  // V^T blocks
    bf16* E = smem;  // [128][136] bf16 (staging LDS is dead)
#pragma unroll
    for (int n = 0; n < 4; ++n) {
      const int cl = wc + n * 16 + r16;
      const long col = colBase + cl;
      const bool primary = col < 1024;
      const float bvv = primary ? bias[col] : bias2[col - 1024];
#pragma unroll
      for (int m = 0; m < 4; ++m) {
#pragma unroll
        for (int r = 0; r < 4; ++r) {
          const int rl = wr + m * 16 + kg * 4 + r;
          float v = acc[m][n][r] + bvv;
          if (MODE == 3 && primary) v *= QSCALE;
          if (tr) E[cl * 136 + rl] = (bf16)v;
          else    E[rl * 136 + cl] = (bf16)v;
        }
      }
    }
    __syncthreads();
    const int er = tid >> 1;          // 0..127 logical row of stored layout
    const int c0 = (tid & 1) * 64;    // 64-elem chunk
    const long brow = rowBase >> 11;  // batch index (tile never straddles)
    const int srow = (int)(rowBase & 2047);
    bf16* dp;
    if (!tr) {
      if (colBase < 1024) {  // Q or K head-split: contiguous along d
        const long col = colBase + c0;
        dp = (bf16*)(void*)D +
             (((brow * NHEADS + (col >> 6)) * SEQ) + srow + er) * HDIM;
      } else {               // C row-major [8192,256]
        dp = D2 + (long)(rowBase + er) * 256 + (colBase - 1024) + c0;
      }
    } else {                 // V^T: contiguous along s
      const long c2 = colBase - 1024 + er;
      dp = D2 + ((brow * NHEADS + (c2 >> 6)) * HDIM + (c2 & 63)) * SEQ +
           srow + c0;
    }
    const bf16* Er = E + er * 136 + c0;
#pragma unroll
    for (int j = 0; j < 8; ++j)
      *(bf16x8*)(dp + j * 8) = *(const bf16x8*)(Er + j * 8);
  }
}

// ---------------- fused non-causal flash attention (R11 structure) ----------
// 512 blocks; XCD-bijective swizzle (8 q-blocks of one head -> 1 XCD).
// 512 threads = 8 waves x 32 q-rows. K/V staged into 3-buffer LDS
// (counted vmcnt(2), one s_barrier/tile); K/V reads XOR-swizzled.
// SWAPPED QK^T: sc = mfma(K, Q) -> D[k][q]; one ds_write_b64 per (qm,kt).
// Row-sum via MFMA ones-fragment (measured faster than lane-local adds:
// DS pipe is the bottleneck, MFMA slots are free). Fixed-max softmax:
// Q pre-scaled, acc starts at C0EXP, p = v_exp2(sc).
__global__ __launch_bounds__(512, 4) void mla_attn(
    const bf16* __restrict__ Q, const bf16* __restrict__ Kg,
    const bf16* __restrict__ Vt, bf16* __restrict__ Out) {
  __shared__ bf16 Kl[3][KVBLK * HDIM];   // 8KB per buf
  __shared__ bf16 Vl[3][HDIM * KVBLK];   // 8KB per buf
  __shared__ bf16 Pl[8][32][64];         // per-wave P tile, swizzled
  const int tid = threadIdx.x;
  const int lane = tid & 63;
  const int w = tid >> 6;
  const int r16 = lane & 15;
  const int kg = lane >> 4;
  // XCD swizzle: physical bid -> logical lb; 8 blocks of a head -> 1 XCD
  const int bid = (int)blockIdx.x;
  const int lb = (bid & 7) * 64 + (bid >> 3);
  const int qb = lb & 7;            // S/256 = 8
  const int bh = lb >> 3;           // b*16 + h
  const bf16* Qp = Q + (long)bh * SEQ * HDIM;
  const bf16* Kp = Kg + (long)bh * SEQ * HDIM;
  const bf16* Vp = Vt + (long)bh * HDIM * SEQ;
  const int q0 = qb * 256 + w * 32;

  // staging geometry: thread stages 16B of K and 16B of V per tile.
  const int so = tid * 16;                                  // 0..8191
  const int srow = so >> 7;                                 // 0..63
  const int scol = ((so & 127) ^ ((srow & 7) << 4)) >> 1;   // elem col
  const bf16* KgS = Kp + (long)srow * HDIM + scol;          // + kv*HDIM
  const bf16* VgS = Vp + (long)srow * SEQ + scol;           // + kv
  const int se = so >> 1;

  // Q fragments [qm][kslice] (already scaled by QSCALE)
  bf16x8 aq[2][2];
#pragma unroll
  for (int qm = 0; qm < 2; ++qm) {
    const bf16* qp = Qp + (long)(q0 + qm * 16 + r16) * HDIM + kg * 8;
    aq[qm][0] = *(const bf16x8*)qp;
    aq[qm][1] = *(const bf16x8*)(qp + 32);
  }

  bf16x8 kones;
#pragma unroll
  for (int j = 0; j < 8; ++j) kones[j] = (bf16)1.0f;

  f32x4 accO[2][4];
  f32x4 lsumv[2] = {{0.f, 0.f, 0.f, 0.f}, {0.f, 0.f, 0.f, 0.f}};
#pragma unroll
  for (int qm = 0; qm < 2; ++qm)
#pragma unroll
    for (int dt = 0; dt < 4; ++dt) accO[qm][dt] = (f32x4){0.f, 0.f, 0.f, 0.f};
  const f32x4 c0v = {C0EXP, C0EXP, C0EXP, C0EXP};

  // swizzled K/V LDS read address (elements)
  auto kaddr = [](const bf16* base, int row, int bytecol) -> const bf16* {
    return base + row * 64 + ((bytecol ^ ((row & 7) << 4)) >> 1);
  };

#define ASTAGE(t_)                                                   \
  {                                                                  \
    const int b_ = (t_) % 3;                                         \
    const long off_ = (long)(t_) * KVBLK;                            \
    gload16(KgS + off_ * HDIM, (bf16*)Kl[b_] + se);                  \
    gload16(VgS + off_, (bf16*)Vl[b_] + se);                         \
  }

  ASTAGE(0);
  ASTAGE(1);
  asm volatile("s_waitcnt vmcnt(2)" ::: "memory");  // tile 0 landed (self)
  asm volatile("s_barrier" ::: "memory");           // -> landed for all

  const int NT = SEQ / KVBLK;
  for (int t = 0; t < NT; ++t) {
    if (t + 2 < NT) {
      ASTAGE(t + 2);
      asm volatile("s_waitcnt vmcnt(2)" ::: "memory");  // tile t+1 landed
    } else {
      asm volatile("s_waitcnt vmcnt(0)" ::: "memory");
    }
    const bf16* kl = Kl[t % 3];
    const bf16* vl = Vl[t % 3];
    // ---- QK^T swapped: sc[qm][kt] = D[k][q], k=kt*16+kg*4+r, q=qm*16+r16
    f32x4 sc[2][4];
    __builtin_amdgcn_s_setprio(1);
#pragma unroll
    for (int kt = 0; kt < 4; ++kt) {
      const int row = kt * 16 + r16;
      const bf16x8 kf0 = *(const bf16x8*)kaddr(kl, row, kg * 16);
      const bf16x8 kf1 = *(const bf16x8*)kaddr(kl, row, 64 + kg * 16);
#pragma unroll
      for (int qm = 0; qm < 2; ++qm) {
        f32x4 tv = mfma16(kf0, aq[qm][0], c0v);
        tv = mfma16(kf1, aq[qm][1], tv);
        sc[qm][kt] = tv;
      }
    }
    __builtin_amdgcn_s_setprio(0);
    // ---- softmax + packed k-major store: one ds_write_b64 per (qm,kt) ----
#pragma unroll
    for (int qm = 0; qm < 2; ++qm) {
      bf16* prow = &Pl[w][qm * 16 + r16][0];
      const int sw = (r16 & 7) << 4;   // byte swizzle
#pragma unroll
      for (int kt = 0; kt < 4; ++kt) {
        bf16x4 pk;
#pragma unroll
        for (int r = 0; r < 4; ++r)
          pk[r] = (bf16)__builtin_amdgcn_exp2f(sc[qm][kt][r]);
        *(bf16x4*)((char*)prow + ((kt * 32 + kg * 8) ^ sw)) = pk;
      }
    }
    // ---- PV + row-sum by MFMA ----
    __builtin_amdgcn_s_setprio(1);
#pragma unroll
    for (int kc = 0; kc < 2; ++kc) {
      bf16x8 ap[2];
#pragma unroll
      for (int qm = 0; qm < 2; ++qm) {
        const bf16* prow = &Pl[w][qm * 16 + r16][0];
        const int sw = (r16 & 7) << 4;
        ap[qm] = *(const bf16x8*)((const char*)prow + ((kc * 64 + kg * 16) ^ sw));
      }
      lsumv[0] = mfma16(ap[0], kones, lsumv[0]);
      lsumv[1] = mfma16(ap[1], kones, lsumv[1]);
#pragma unroll
      for (int dt = 0; dt < 4; ++dt) {
        const int vrow = dt * 16 + r16;
        const bf16x8 vf = *(const bf16x8*)kaddr(vl, vrow, kc * 64 + kg * 16);
        accO[0][dt] = mfma16(ap[0], vf, accO[0][dt]);
        accO[1][dt] = mfma16(ap[1], vf, accO[1][dt]);
      }
    }
    __builtin_amdgcn_s_setprio(0);
    asm volatile("s_barrier" ::: "memory");
  }
#undef ASTAGE

  const int b = bh >> 4, h = bh & 15;
#pragma unroll
  for (int qm = 0; qm < 2; ++qm)
#pragma unroll
    for (int r = 0; r < 4; ++r) {
      const float inv = 1.f / lsumv[qm][r];   // rowsum, same in every col
      const long qrow = q0 + qm * 16 + kg * 4 + r;
      bf16* op = Out + ((long)b * SEQ + qrow) * DMODEL + h * HDIM;
#pragma unroll
      for (int dt = 0; dt < 4; ++dt)
        op[dt * 16 + r16] = (bf16)(accO[qm][dt][r] * inv);
    }
}

// ---------------- launcher ----------------
extern "C" void kernel_launch(void* const* d_in, const int* in_sizes, int n_in,
                              void* d_out, int out_size, void* d_ws, size_t ws_size,
                              hipStream_t stream) {
  const float* x  = (const float*)d_in[0];
  const float* Wc = (const float*)d_in[1];
  const float* bc = (const float*)d_in[2];
  const float* Wk = (const float*)d_in[3];
  const float* bk = (const float*)d_in[4];
  const float* Wv = (const float*)d_in[5];
  const float* bv = (const float*)d_in[6];
  const float* Wq = (const float*)d_in[7];
  const float* bq = (const float*)d_in[8];
  const float* Wo = (const float*)d_in[9];
  const float* bo = (const float*)d_in[10];
  float* out = (float*)d_out;

  bf16* p = (bf16*)d_ws;
  bf16* xb   = p; p += (long)NTOK * 1024;   // also reused as AO
  bf16* WqcT = p; p += 1280 * 1024;         // Wq^T rows 0..1023, Wc^T rows 1024..1279
  bf16* WkvT = p; p += 2048 * 256;          // Wk^T rows 0..1023, Wv^T rows 1024..2047
  bf16* WoT  = p; p += 1024 * 1024;
  bf16* Qb   = p; p += (long)NTOK * 1024;
  bf16* Kb   = p; p += (long)NTOK * 1024;
  bf16* Vtb  = p; p += (long)NTOK * 1024;
  bf16* Cb   = p; p += (long)NTOK * 256;
  bf16* AO   = xb;  // alias: x is dead after the QC GEMM

  // one fused prep launch: x cvt + all 5 weight transposes
  prep_all<<<6912, 256, 0, stream>>>(x, Wc, Wk, Wv, Wq, Wo, xb, WqcT, WkvT, WoT);

  // fused Q|C: Q -> [B,H,S,64] (scaled), C -> [8192,256]
  gemm_bt<3, bf16><<<dim3(64, 10), 256, 0, stream>>>(xb, WqcT, bq, bc, Qb, Cb, 1280, 1024);
  // fused K|V: K -> [B,H,S,64], V -> [B,H,64,S]
  gemm_bt<4, bf16><<<dim3(64, 16), 256, 0, stream>>>(Cb, WkvT, bk, bv, Kb, Vtb, 2048, 256);

  mla_attn<<<(SEQ / 256) * BATCH * NHEADS, 512, 0, stream>>>(Qb, Kb, Vtb, AO);

  // out = AO*Wo+bo -> f32 [8192,1024]
  gemm_bt<0, float><<<dim3(64, 8), 256, 0, stream>>>(AO, WoT, bo, bo, out, (bf16*)nullptr, 1024, 1024);
}